// Round 1
// baseline (441.146 us; speedup 1.0000x reference)
//
#include <hip/hip_runtime.h>
#include <hip/hip_bf16.h>
#include <math.h>

#define B_ 16
#define N_ 1024
#define KNN_K 16
#define F_ 64
#define H_ 64
#define LN_EPS 1e-5f

typedef unsigned long long u64;
typedef unsigned int u32;

// ---------------------------------------------------------------------------
// prep: blocks 0..3 transpose Wh[l][o][i] -> WhT[l][i][o]; blocks 4..19 count
// n_tracks[b] = sum(mask[b,:]).
// ---------------------------------------------------------------------------
__global__ __launch_bounds__(256) void prep_kernel(const float* __restrict__ Wh,
                                                   float* __restrict__ WhT,
                                                   const int* __restrict__ mask,
                                                   float* __restrict__ ntr) {
  int blk = blockIdx.x;
  int t = threadIdx.x;
  if (blk < 4) {
    int l = blk;
    for (int e = t; e < 4096; e += 256) {
      int o = e >> 6, i = e & 63;
      WhT[l * 4096 + i * 64 + o] = Wh[l * 4096 + o * 64 + i];
    }
  } else {
    int b = blk - 4;
    int s = 0;
    for (int e = t; e < N_; e += 256) s += mask[b * N_ + e];
    for (int off = 32; off; off >>= 1) s += __shfl_xor(s, off, 64);
    __shared__ int acc[4];
    int wave = t >> 6, lane = t & 63;
    if (lane == 0) acc[wave] = s;
    __syncthreads();
    if (t == 0) ntr[b] = (float)(acc[0] + acc[1] + acc[2] + acc[3]);
  }
}

// ---------------------------------------------------------------------------
// knn: one wave per query point. Key = (bits(d^2 [+inf if masked]) << 32) | j,
// lexicographic min == smallest distance, ties -> lowest index (matches
// jax.lax.top_k on -dist). fp contract off so d^2 matches numpy f32 exactly.
// ---------------------------------------------------------------------------
__global__ __launch_bounds__(256) void knn_kernel(const float* __restrict__ points,
                                                  const int* __restrict__ mask,
                                                  int* __restrict__ knn) {
#pragma clang fp contract(off)
  __shared__ float px[N_], py[N_], pz[N_], minf[N_];
  int b = blockIdx.x >> 8;
  int qbase = (blockIdx.x & 255) << 2;
  int t = threadIdx.x;
  for (int j = t; j < N_; j += 256) {
    const float* p = points + ((size_t)(b * N_ + j)) * 3;
    px[j] = p[0];
    py[j] = p[1];
    pz[j] = p[2];
    minf[j] = mask[b * N_ + j] ? 0.0f : __builtin_inff();
  }
  __syncthreads();
  int wave = t >> 6, lane = t & 63;
  int n = qbase + wave;
  float qx = px[n], qy = py[n], qz = pz[n];
  u64 key[16];
#pragma unroll
  for (int c = 0; c < 16; c++) {
    int j = lane + (c << 6);
    float dx = qx - px[j];
    float dy = qy - py[j];
    float dz = qz - pz[j];
    float d2 = dx * dx + dy * dy + dz * dz;
    d2 = d2 + minf[j];
    key[c] = ((u64)__float_as_uint(d2) << 32) | (u32)j;
  }
  int* dst = knn + ((size_t)(b * N_ + n)) * KNN_K;
  for (int s = 0; s < 16; s++) {
    u64 m = key[0];
#pragma unroll
    for (int c = 1; c < 16; c++) m = key[c] < m ? key[c] : m;
#pragma unroll
    for (int off = 32; off; off >>= 1) {
      u64 o = __shfl_xor(m, off, 64);
      if (o < m) m = o;
    }
    if (lane == 0) dst[s] = (int)(m & 0xFFFFFFFFu);
#pragma unroll
    for (int c = 0; c < 16; c++)
      if (key[c] == m) key[c] = ~0ULL;
  }
}

// ---------------------------------------------------------------------------
// precompute: p_c[p] = x[p] @ (W0a+W0b)^T + b0 ; p_n[p] = x[p] @ W0b^T.
// Wave per point; lane = output o; W staged transposed in LDS (stride-1 reads,
// conflict-free); x row via wave-uniform scalar loads.
// ---------------------------------------------------------------------------
__global__ __launch_bounds__(256) void precompute_kernel(const float* __restrict__ x,
                                                         const float* __restrict__ W0,
                                                         const float* __restrict__ b0,
                                                         float* __restrict__ p_c,
                                                         float* __restrict__ p_n) {
  __shared__ float Wc[64][64];  // [i][o] = W0[o][i] + W0[o][i+64]
  __shared__ float Wn[64][64];  // [i][o] = W0[o][i+64]
  int t = threadIdx.x;
  for (int e = t; e < 4096; e += 256) {
    int o = e >> 6, i = e & 63;
    float wa = W0[o * 128 + i];
    float wb = W0[o * 128 + 64 + i];
    Wc[i][o] = wa + wb;
    Wn[i][o] = wb;
  }
  __syncthreads();
  int wave = t >> 6, lane = t & 63;
  int pbase = blockIdx.x * 64 + wave * 16;
  for (int it = 0; it < 16; it++) {
    int p = pbase + it;
    const float* xr = x + (size_t)__builtin_amdgcn_readfirstlane(p) * 64;
    float pc = b0[lane];
    float pn = 0.0f;
#pragma unroll
    for (int i = 0; i < 64; i++) {
      float xi = xr[i];
      pc = fmaf(xi, Wc[i][lane], pc);
      pn = fmaf(xi, Wn[i][lane], pn);
    }
    p_c[(size_t)p * 64 + lane] = pc;
    p_n[(size_t)p * 64 + lane] = pn;
  }
}

// ---------------------------------------------------------------------------
// mlp: thread per edge. Lane layout: lane = k + 16*(point-in-wave) so the
// K-aggregation is a 16-lane shfl_xor reduce. h[64]/hn[64] in registers
// (all indices compile-time). Hidden weights WhT[l][i][o]: wave-uniform
// addresses -> s_load stream, v_fmac v,s,v; 64 independent accumulators.
// ---------------------------------------------------------------------------
__global__ __launch_bounds__(256, 2) void mlp_kernel(const float* __restrict__ p_c,
                                                     const float* __restrict__ p_n,
                                                     const int* __restrict__ knn,
                                                     const float* __restrict__ WhT,
                                                     const float* __restrict__ bh,
                                                     const float* __restrict__ ln_g,
                                                     const float* __restrict__ ln_b,
                                                     const float* __restrict__ prelu_a,
                                                     const float* __restrict__ ntr,
                                                     float* __restrict__ out) {
  int t = threadIdx.x;
  int T = blockIdx.x * 256 + t;
  int p = T >> 4;   // global point index (b*1024+n)
  int k = T & 15;   // neighbor slot
  int b = p >> 10;
  int j = knn[(size_t)p * 16 + k];
  const float4* pc4 = reinterpret_cast<const float4*>(p_c + (size_t)p * 64);
  const float4* pn4 = reinterpret_cast<const float4*>(p_n + (size_t)((b << 10) + j) * 64);
  float h[64];
#pragma unroll
  for (int c = 0; c < 16; c++) {
    float4 a = pc4[c], v = pn4[c];
    h[c * 4 + 0] = a.x - v.x;
    h[c * 4 + 1] = a.y - v.y;
    h[c * 4 + 2] = a.z - v.z;
    h[c * 4 + 3] = a.w - v.w;
  }
  // LN + PReLU, params index 0
  {
    float s = 0.0f, s2 = 0.0f;
#pragma unroll
    for (int o = 0; o < 64; o++) { s += h[o]; s2 += h[o] * h[o]; }
    float mu = s * (1.0f / 64.0f);
    float var = s2 * (1.0f / 64.0f) - mu * mu;
    float inv = rsqrtf(var + LN_EPS);
    float aslope = prelu_a[0];
#pragma unroll
    for (int o = 0; o < 64; o++) {
      float v = ln_g[o] * ((h[o] - mu) * inv) + ln_b[o];
      h[o] = v > 0.0f ? v : aslope * v;
    }
  }
  // 4 hidden layers
#pragma unroll 1
  for (int l = 0; l < 4; l++) {
    const float* W = WhT + l * 4096;     // [i][o]
    const float* bias = bh + l * 64;
    float hn[64];
#pragma unroll
    for (int o = 0; o < 64; o++) hn[o] = bias[o];
#pragma unroll
    for (int i = 0; i < 64; i++) {
      float hi = h[i];
#pragma unroll
      for (int o = 0; o < 64; o++) hn[o] = fmaf(W[i * 64 + o], hi, hn[o]);
    }
    float s = 0.0f, s2 = 0.0f;
#pragma unroll
    for (int o = 0; o < 64; o++) { s += hn[o]; s2 += hn[o] * hn[o]; }
    float mu = s * (1.0f / 64.0f);
    float var = s2 * (1.0f / 64.0f) - mu * mu;
    float inv = rsqrtf(var + LN_EPS);
    float aslope = prelu_a[l + 1];
    const float* g = ln_g + (l + 1) * 64;
    const float* be = ln_b + (l + 1) * 64;
#pragma unroll
    for (int o = 0; o < 64; o++) {
      float v = g[o] * ((hn[o] - mu) * inv) + be[o];
      h[o] = v > 0.0f ? v : aslope * v;
    }
  }
  // masked mean over K (nm[k] = k < n_tracks; divide by n_safe)
  float cnt = ntr[b];
  float w = ((float)k < cnt) ? 1.0f : 0.0f;
  float n_safe = (cnt == 0.0f) ? 1.0f : cnt;
  float rinv = 1.0f / n_safe;
#pragma unroll
  for (int o = 0; o < 64; o++) {
    float v = h[o] * w;
    v += __shfl_xor(v, 1, 64);
    v += __shfl_xor(v, 2, 64);
    v += __shfl_xor(v, 4, 64);
    v += __shfl_xor(v, 8, 64);
    h[o] = v * rinv;
  }
  if (k == 0) {
    float4* o4 = reinterpret_cast<float4*>(out + (size_t)p * 64);
#pragma unroll
    for (int c = 0; c < 16; c++) {
      float4 v;
      v.x = h[c * 4 + 0];
      v.y = h[c * 4 + 1];
      v.z = h[c * 4 + 2];
      v.w = h[c * 4 + 3];
      o4[c] = v;
    }
  }
}

// ---------------------------------------------------------------------------
extern "C" void kernel_launch(void* const* d_in, const int* in_sizes, int n_in,
                              void* d_out, int out_size, void* d_ws, size_t ws_size,
                              hipStream_t stream) {
  const float* points  = (const float*)d_in[0];
  const float* x       = (const float*)d_in[1];
  const int*   mask    = (const int*)d_in[2];
  const float* W0      = (const float*)d_in[3];
  const float* b0      = (const float*)d_in[4];
  const float* Wh      = (const float*)d_in[5];
  const float* bh      = (const float*)d_in[6];
  const float* ln_g    = (const float*)d_in[7];
  const float* ln_b    = (const float*)d_in[8];
  const float* prelu_a = (const float*)d_in[9];
  float* out = (float*)d_out;

  char* ws = (char*)d_ws;
  int*   knn  = (int*)ws;                                   // 1 MB
  float* p_c  = (float*)(ws + (1 << 20));                   // 4 MB
  float* p_n  = (float*)(ws + (1 << 20) + (4 << 20));       // 4 MB
  float* WhT  = (float*)(ws + (1 << 20) + (8 << 20));       // 64 KB
  float* ntr  = (float*)(ws + (1 << 20) + (8 << 20) + 65536);

  prep_kernel<<<20, 256, 0, stream>>>(Wh, WhT, mask, ntr);
  knn_kernel<<<4096, 256, 0, stream>>>(points, mask, knn);
  precompute_kernel<<<256, 256, 0, stream>>>(x, W0, b0, p_c, p_n);
  mlp_kernel<<<1024, 256, 0, stream>>>(p_c, p_n, knn, WhT, bh, ln_g, ln_b, prelu_a, ntr, out);
}

// Round 2
// 276.436 us; speedup vs baseline: 1.5958x; 1.5958x over previous
//
#include <hip/hip_runtime.h>
#include <hip/hip_bf16.h>
#include <math.h>

#define B_ 16
#define N_ 1024
#define KNN_K 16
#define F_ 64
#define H_ 64
#define LN_EPS 1e-5f

typedef unsigned long long u64;
typedef unsigned int u32;

// ---------------------------------------------------------------------------
// prep: blocks 0..3 transpose Wh[l][o][i] -> WhT[l][i][o]; blocks 4..19 count
// n_tracks[b] = sum(mask[b,:]).
// ---------------------------------------------------------------------------
__global__ __launch_bounds__(256) void prep_kernel(const float* __restrict__ Wh,
                                                   float* __restrict__ WhT,
                                                   const int* __restrict__ mask,
                                                   float* __restrict__ ntr) {
  int blk = blockIdx.x;
  int t = threadIdx.x;
  if (blk < 4) {
    int l = blk;
    for (int e = t; e < 4096; e += 256) {
      int o = e >> 6, i = e & 63;
      WhT[l * 4096 + i * 64 + o] = Wh[l * 4096 + o * 64 + i];
    }
  } else {
    int b = blk - 4;
    int s = 0;
    for (int e = t; e < N_; e += 256) s += mask[b * N_ + e];
    for (int off = 32; off; off >>= 1) s += __shfl_xor(s, off, 64);
    __shared__ int acc[4];
    int wave = t >> 6, lane = t & 63;
    if (lane == 0) acc[wave] = s;
    __syncthreads();
    if (t == 0) ntr[b] = (float)(acc[0] + acc[1] + acc[2] + acc[3]);
  }
}

// ---------------------------------------------------------------------------
// knn: one wave per query point. Key = (bits(d^2 [+inf if masked]) << 32) | j,
// lexicographic min == smallest distance, ties -> lowest index (matches
// jax.lax.top_k on -dist). fp contract off so d^2 matches numpy f32 exactly.
// ---------------------------------------------------------------------------
__global__ __launch_bounds__(256) void knn_kernel(const float* __restrict__ points,
                                                  const int* __restrict__ mask,
                                                  int* __restrict__ knn) {
#pragma clang fp contract(off)
  __shared__ float px[N_], py[N_], pz[N_], minf[N_];
  int b = blockIdx.x >> 8;
  int qbase = (blockIdx.x & 255) << 2;
  int t = threadIdx.x;
  for (int j = t; j < N_; j += 256) {
    const float* p = points + ((size_t)(b * N_ + j)) * 3;
    px[j] = p[0];
    py[j] = p[1];
    pz[j] = p[2];
    minf[j] = mask[b * N_ + j] ? 0.0f : __builtin_inff();
  }
  __syncthreads();
  int wave = t >> 6, lane = t & 63;
  int n = qbase + wave;
  float qx = px[n], qy = py[n], qz = pz[n];
  u64 key[16];
#pragma unroll
  for (int c = 0; c < 16; c++) {
    int j = lane + (c << 6);
    float dx = qx - px[j];
    float dy = qy - py[j];
    float dz = qz - pz[j];
    float d2 = dx * dx + dy * dy + dz * dz;
    d2 = d2 + minf[j];
    key[c] = ((u64)__float_as_uint(d2) << 32) | (u32)j;
  }
  int* dst = knn + ((size_t)(b * N_ + n)) * KNN_K;
  for (int s = 0; s < 16; s++) {
    u64 m = key[0];
#pragma unroll
    for (int c = 1; c < 16; c++) m = key[c] < m ? key[c] : m;
#pragma unroll
    for (int off = 32; off; off >>= 1) {
      u64 o = __shfl_xor(m, off, 64);
      if (o < m) m = o;
    }
    if (lane == 0) dst[s] = (int)(m & 0xFFFFFFFFu);
#pragma unroll
    for (int c = 0; c < 16; c++)
      if (key[c] == m) key[c] = ~0ULL;
  }
}

// ---------------------------------------------------------------------------
// precompute: p_c[p] = x[p] @ (W0a+W0b)^T + b0 ; p_n[p] = x[p] @ W0b^T.
// ---------------------------------------------------------------------------
__global__ __launch_bounds__(256) void precompute_kernel(const float* __restrict__ x,
                                                         const float* __restrict__ W0,
                                                         const float* __restrict__ b0,
                                                         float* __restrict__ p_c,
                                                         float* __restrict__ p_n) {
  __shared__ float Wc[64][64];  // [i][o] = W0[o][i] + W0[o][i+64]
  __shared__ float Wn[64][64];  // [i][o] = W0[o][i+64]
  int t = threadIdx.x;
  for (int e = t; e < 4096; e += 256) {
    int o = e >> 6, i = e & 63;
    float wa = W0[o * 128 + i];
    float wb = W0[o * 128 + 64 + i];
    Wc[i][o] = wa + wb;
    Wn[i][o] = wb;
  }
  __syncthreads();
  int wave = t >> 6, lane = t & 63;
  int pbase = blockIdx.x * 64 + wave * 16;
  for (int it = 0; it < 16; it++) {
    int p = pbase + it;
    const float* xr = x + (size_t)__builtin_amdgcn_readfirstlane(p) * 64;
    float pc = b0[lane];
    float pn = 0.0f;
#pragma unroll
    for (int i = 0; i < 64; i++) {
      float xi = xr[i];
      pc = fmaf(xi, Wc[i][lane], pc);
      pn = fmaf(xi, Wn[i][lane], pn);
    }
    p_c[(size_t)p * 64 + lane] = pc;
    p_n[(size_t)p * 64 + lane] = pn;
  }
}

// ---------------------------------------------------------------------------
// mlp: thread per edge, 128 thr/block. Layer input h lives in a PRIVATE LDS
// column (hbuf[i][tid], bank = tid%32 -> 2 lanes/bank = conflict-free, no
// barriers), so all 64 accumulators stay in VGPRs and each weight row
// (wave-uniform s_load stream) is read ONCE with 64 FMAs to hide it.
// i-loop unrolled x8 so ~8 rows of s_loads pipeline.
// ---------------------------------------------------------------------------
__global__ __launch_bounds__(128) void mlp_kernel(const float* __restrict__ p_c,
                                                  const float* __restrict__ p_n,
                                                  const int* __restrict__ knn,
                                                  const float* __restrict__ WhT,
                                                  const float* __restrict__ bh,
                                                  const float* __restrict__ ln_g,
                                                  const float* __restrict__ ln_b,
                                                  const float* __restrict__ prelu_a,
                                                  const float* __restrict__ ntr,
                                                  float* __restrict__ out) {
  __shared__ float hbuf[64 * 128];  // [i][tid] columns, 32 KiB
  int tid = threadIdx.x;
  int T = blockIdx.x * 128 + tid;
  int p = T >> 4;   // global point index (b*1024+n)
  int k = T & 15;   // neighbor slot
  int b = p >> 10;
  int j = knn[(size_t)p * 16 + k];
  const float4* pc4 = reinterpret_cast<const float4*>(p_c + (size_t)p * 64);
  const float4* pn4 = reinterpret_cast<const float4*>(p_n + (size_t)((b << 10) + j) * 64);
  float h[64];
#pragma unroll
  for (int c = 0; c < 16; c++) {
    float4 a = pc4[c], v = pn4[c];
    h[c * 4 + 0] = a.x - v.x;
    h[c * 4 + 1] = a.y - v.y;
    h[c * 4 + 2] = a.z - v.z;
    h[c * 4 + 3] = a.w - v.w;
  }
  // LN + PReLU, params index 0; write to LDS column
  {
    float s = 0.0f, s2 = 0.0f;
#pragma unroll
    for (int o = 0; o < 64; o++) { s += h[o]; s2 += h[o] * h[o]; }
    float mu = s * (1.0f / 64.0f);
    float var = s2 * (1.0f / 64.0f) - mu * mu;
    float inv = rsqrtf(var + LN_EPS);
    float aslope = prelu_a[0];
#pragma unroll
    for (int o = 0; o < 64; o++) {
      float v = ln_g[o] * ((h[o] - mu) * inv) + ln_b[o];
      v = v > 0.0f ? v : aslope * v;
      hbuf[o * 128 + tid] = v;
    }
  }
  // 4 hidden layers: acc[64] in regs, h streamed from private LDS column
#pragma unroll 1
  for (int l = 0; l < 4; l++) {
    const float* W = WhT + l * 4096;     // [i][o]
    const float* bias = bh + l * 64;
    float acc[64];
#pragma unroll
    for (int o = 0; o < 64; o++) acc[o] = bias[o];
#pragma unroll 8
    for (int i = 0; i < 64; i++) {
      float hi = hbuf[i * 128 + tid];
      const float* Wr = W + i * 64;
#pragma unroll
      for (int o = 0; o < 64; o++) acc[o] = fmaf(Wr[o], hi, acc[o]);
    }
    float s = 0.0f, s2 = 0.0f;
#pragma unroll
    for (int o = 0; o < 64; o++) { s += acc[o]; s2 += acc[o] * acc[o]; }
    float mu = s * (1.0f / 64.0f);
    float var = s2 * (1.0f / 64.0f) - mu * mu;
    float inv = rsqrtf(var + LN_EPS);
    float aslope = prelu_a[l + 1];
    const float* g = ln_g + (l + 1) * 64;
    const float* be = ln_b + (l + 1) * 64;
    if (l < 3) {
#pragma unroll
      for (int o = 0; o < 64; o++) {
        float v = g[o] * ((acc[o] - mu) * inv) + be[o];
        v = v > 0.0f ? v : aslope * v;
        hbuf[o * 128 + tid] = v;
      }
    } else {
#pragma unroll
      for (int o = 0; o < 64; o++) {
        float v = g[o] * ((acc[o] - mu) * inv) + be[o];
        h[o] = v > 0.0f ? v : aslope * v;
      }
    }
  }
  // masked mean over K (nm[k] = k < n_tracks; divide by n_safe)
  float cnt = ntr[b];
  float w = ((float)k < cnt) ? 1.0f : 0.0f;
  float n_safe = (cnt == 0.0f) ? 1.0f : cnt;
  float rinv = 1.0f / n_safe;
#pragma unroll
  for (int o = 0; o < 64; o++) {
    float v = h[o] * w;
    v += __shfl_xor(v, 1, 64);
    v += __shfl_xor(v, 2, 64);
    v += __shfl_xor(v, 4, 64);
    v += __shfl_xor(v, 8, 64);
    h[o] = v * rinv;
  }
  if (k == 0) {
    float4* o4 = reinterpret_cast<float4*>(out + (size_t)p * 64);
#pragma unroll
    for (int c = 0; c < 16; c++) {
      float4 v;
      v.x = h[c * 4 + 0];
      v.y = h[c * 4 + 1];
      v.z = h[c * 4 + 2];
      v.w = h[c * 4 + 3];
      o4[c] = v;
    }
  }
}

// ---------------------------------------------------------------------------
extern "C" void kernel_launch(void* const* d_in, const int* in_sizes, int n_in,
                              void* d_out, int out_size, void* d_ws, size_t ws_size,
                              hipStream_t stream) {
  const float* points  = (const float*)d_in[0];
  const float* x       = (const float*)d_in[1];
  const int*   mask    = (const int*)d_in[2];
  const float* W0      = (const float*)d_in[3];
  const float* b0      = (const float*)d_in[4];
  const float* Wh      = (const float*)d_in[5];
  const float* bh      = (const float*)d_in[6];
  const float* ln_g    = (const float*)d_in[7];
  const float* ln_b    = (const float*)d_in[8];
  const float* prelu_a = (const float*)d_in[9];
  float* out = (float*)d_out;

  char* ws = (char*)d_ws;
  int*   knn  = (int*)ws;                                   // 1 MB
  float* p_c  = (float*)(ws + (1 << 20));                   // 4 MB
  float* p_n  = (float*)(ws + (1 << 20) + (4 << 20));       // 4 MB
  float* WhT  = (float*)(ws + (1 << 20) + (8 << 20));       // 64 KB
  float* ntr  = (float*)(ws + (1 << 20) + (8 << 20) + 65536);

  prep_kernel<<<20, 256, 0, stream>>>(Wh, WhT, mask, ntr);
  knn_kernel<<<4096, 256, 0, stream>>>(points, mask, knn);
  precompute_kernel<<<256, 256, 0, stream>>>(x, W0, b0, p_c, p_n);
  mlp_kernel<<<2048, 128, 0, stream>>>(p_c, p_n, knn, WhT, bh, ln_g, ln_b, prelu_a, ntr, out);
}

// Round 9
// 271.374 us; speedup vs baseline: 1.6256x; 1.0187x over previous
//
#include <hip/hip_runtime.h>
#include <hip/hip_bf16.h>
#include <math.h>

#define N_ 1024
#define KNN_K 16
#define LN_EPS 1e-5f

typedef unsigned long long u64;
typedef unsigned int u32;
typedef __attribute__((ext_vector_type(4))) float f32x4;
typedef __attribute__((ext_vector_type(8))) short short8;
typedef __attribute__((ext_vector_type(4))) unsigned int u32x4;

// Round-to-nearest-even bf16 helpers.
__device__ __forceinline__ u32 rn_hi32(float v) {  // bf16 bits in high half
  u32 u = __float_as_uint(v);
  return (u + 0x7FFFu + ((u >> 16) & 1u)) & 0xFFFF0000u;
}
__device__ __forceinline__ u32 rn_b16(float v) {   // bf16 bits as 16-bit value
  u32 u = __float_as_uint(v);
  return (u + 0x7FFFu + ((u >> 16) & 1u)) >> 16;
}

// ---------------------------------------------------------------------------
// prep: blocks 0..7 MFMA A-fragments (all 4 layers); blocks 8..11 WhT for the
// scalar engine; blocks 12..27 ntr.
// ---------------------------------------------------------------------------
__global__ __launch_bounds__(256) void prep_kernel(const float* __restrict__ Wh,
                                                   u32x4* __restrict__ whi,
                                                   u32x4* __restrict__ wlo,
                                                   float* __restrict__ WhT,
                                                   const int* __restrict__ mask,
                                                   float* __restrict__ ntr) {
  int blk = blockIdx.x;
  int t = threadIdx.x;
  if (blk < 8) {
    int idx = blk * 256 + t;              // 0..2047
    int lane = idx & 63;
    int ks = (idx >> 6) & 1;
    int m = (idx >> 7) & 3;
    int li = idx >> 9;
    int o = 16 * m + (lane & 15);
    int k0 = 32 * ks + 8 * (lane >> 4);
    const float* w = Wh + li * 4096 + o * 64 + k0;
    u32x4 hi, lo;
#pragma unroll
    for (int j = 0; j < 4; j++) {
      float f0 = w[2 * j], f1 = w[2 * j + 1];
      u32 h0 = rn_hi32(f0);
      u32 h1 = rn_hi32(f1);
      float l0 = f0 - __uint_as_float(h0);
      float l1 = f1 - __uint_as_float(h1);
      hi[j] = (h0 >> 16) | h1;
      lo[j] = rn_b16(l0) | (rn_b16(l1) << 16);
    }
    int fi = ((li * 4 + m) * 2 + ks) * 64 + lane;
    whi[fi] = hi;
    wlo[fi] = lo;
  } else if (blk < 12) {
    int l2 = blk - 8;
    for (int e = t; e < 4096; e += 256) {
      int o = e >> 6, i = e & 63;
      WhT[l2 * 4096 + i * 64 + o] = Wh[l2 * 4096 + o * 64 + i];
    }
  } else {
    int b = blk - 12;
    int s = 0;
    for (int e = t; e < N_; e += 256) s += mask[b * N_ + e];
    for (int off = 32; off; off >>= 1) s += __shfl_xor(s, off, 64);
    __shared__ int acc[4];
    int wave = t >> 6, lane = t & 63;
    if (lane == 0) acc[wave] = s;
    __syncthreads();
    if (t == 0) ntr[b] = (float)(acc[0] + acc[1] + acc[2] + acc[3]);
  }
}

// ---------------------------------------------------------------------------
// knn: EXACT R2-proven form (picks == reference picks on this dataset).
// ---------------------------------------------------------------------------
__global__ __launch_bounds__(256) void knn_kernel(const float* __restrict__ points,
                                                  const int* __restrict__ mask,
                                                  int* __restrict__ knn) {
#pragma clang fp contract(off)
  __shared__ float px[N_], py[N_], pz[N_], minf[N_];
  int b = blockIdx.x >> 8;
  int qbase = (blockIdx.x & 255) << 2;
  int t = threadIdx.x;
  for (int j = t; j < N_; j += 256) {
    const float* p = points + ((size_t)(b * N_ + j)) * 3;
    px[j] = p[0];
    py[j] = p[1];
    pz[j] = p[2];
    minf[j] = mask[b * N_ + j] ? 0.0f : __builtin_inff();
  }
  __syncthreads();
  int wave = t >> 6, lane = t & 63;
  int n = qbase + wave;
  float qx = px[n], qy = py[n], qz = pz[n];
  u64 key[16];
#pragma unroll
  for (int c = 0; c < 16; c++) {
    int j = lane + (c << 6);
    float dx = qx - px[j];
    float dy = qy - py[j];
    float dz = qz - pz[j];
    float d2 = dx * dx + dy * dy + dz * dz;
    d2 = d2 + minf[j];
    key[c] = ((u64)__float_as_uint(d2) << 32) | (u32)j;
  }
  int* dst = knn + ((size_t)(b * N_ + n)) * KNN_K;
  for (int s = 0; s < 16; s++) {
    u64 m = key[0];
#pragma unroll
    for (int c = 1; c < 16; c++) m = key[c] < m ? key[c] : m;
#pragma unroll
    for (int off = 32; off; off >>= 1) {
      u64 o = __shfl_xor(m, off, 64);
      if (o < m) m = o;
    }
    if (lane == 0) dst[s] = (int)(m & 0xFFFFFFFFu);
#pragma unroll
    for (int c = 0; c < 16; c++)
      if (key[c] == m) key[c] = ~0ULL;
  }
}

// ---------------------------------------------------------------------------
// precompute: unchanged (verified).
// ---------------------------------------------------------------------------
__global__ __launch_bounds__(256) void precompute_kernel(const float* __restrict__ x,
                                                         const float* __restrict__ W0,
                                                         const float* __restrict__ b0,
                                                         float* __restrict__ p_c,
                                                         float* __restrict__ p_n) {
  __shared__ float Wc[64][64];
  __shared__ float Wn[64][64];
  int t = threadIdx.x;
  for (int e = t; e < 4096; e += 256) {
    int o = e >> 6, i = e & 63;
    float wa = W0[o * 128 + i];
    float wb = W0[o * 128 + 64 + i];
    Wc[i][o] = wa + wb;
    Wn[i][o] = wb;
  }
  __syncthreads();
  int wave = t >> 6, lane = t & 63;
  int pbase = blockIdx.x * 64 + wave * 16;
  for (int it = 0; it < 16; it++) {
    int p = pbase + it;
    const float* xr = x + (size_t)__builtin_amdgcn_readfirstlane(p) * 64;
    float pc = b0[lane];
    float pn = 0.0f;
#pragma unroll
    for (int i = 0; i < 64; i++) {
      float xi = xr[i];
      pc = fmaf(xi, Wc[i][lane], pc);
      pn = fmaf(xi, Wn[i][lane], pn);
    }
    p_c[(size_t)p * 64 + lane] = pc;
    p_n[(size_t)p * 64 + lane] = pn;
  }
}

// ---------------------------------------------------------------------------
// mlp_hybrid2 — BISECT, LDS ELIMINATED FROM MFMA STAGE:
//   layers 0..2: R2-proven scalar engine (hbuf private columns).
//   layer 3: MFMA, B-fragments built from REGISTERS via __shfl (no LDS H at
//   all: no swizzle, no vector-LDS alignment, no barriers).
//   PASS  -> R3-R8 bug was in the H-LDS pipeline.
//   FAIL  -> bug is in fragments / MFMA layout conventions.
// ---------------------------------------------------------------------------
__global__ __launch_bounds__(128) void mlp_hybrid2_kernel(
    const float* __restrict__ p_c, const float* __restrict__ p_n,
    const int* __restrict__ knn_, const float* __restrict__ WhT,
    const u32x4* __restrict__ whi, const u32x4* __restrict__ wlo,
    const float* __restrict__ bh, const float* __restrict__ ln_g,
    const float* __restrict__ ln_b, const float* __restrict__ prelu_a,
    const float* __restrict__ ntr, float* __restrict__ out) {
  __shared__ float hbuf[8192];            // 32 KiB, per-thread private columns
  const int t = threadIdx.x;
  const int wv = t >> 6, l = t & 63;
  const int c = l & 15;                   // neighbor slot k
  const int g = l >> 4;                   // point-in-wave / k-octet group
  const int pbase = blockIdx.x * 8 + wv * 4;
  const int b = pbase >> 10;
  float h[64];

  // ---- layer 0 (scalar, R2-exact math): edge (p0 = pbase+g, slot c) ----
  {
    int p0 = pbase + g;
    int j = knn_[(size_t)p0 * 16 + c];
    const float4* pc4 = reinterpret_cast<const float4*>(p_c + (size_t)p0 * 64);
    const float4* pn4 = reinterpret_cast<const float4*>(p_n + (size_t)((b << 10) + j) * 64);
#pragma unroll
    for (int q = 0; q < 16; q++) {
      float4 a = pc4[q], v = pn4[q];
      h[q * 4 + 0] = a.x - v.x;
      h[q * 4 + 1] = a.y - v.y;
      h[q * 4 + 2] = a.z - v.z;
      h[q * 4 + 3] = a.w - v.w;
    }
    float s = 0.0f, s2 = 0.0f;
#pragma unroll
    for (int o = 0; o < 64; o++) { s += h[o]; s2 += h[o] * h[o]; }
    float mu = s * (1.0f / 64.0f);
    float var = s2 * (1.0f / 64.0f) - mu * mu;
    float inv = rsqrtf(var + LN_EPS);
    float aslope = prelu_a[0];
#pragma unroll
    for (int o = 0; o < 64; o++) {
      float v = ln_g[o] * ((h[o] - mu) * inv) + ln_b[o];
      v = v > 0.0f ? v : aslope * v;
      hbuf[o * 128 + t] = v;
    }
  }

  // ---- hidden layers 0..2: R2-proven scalar loop ----
#pragma unroll 1
  for (int li = 0; li < 3; li++) {
    const float* W = WhT + li * 4096;
    const float* bias = bh + li * 64;
    float acc_s[64];
#pragma unroll
    for (int o = 0; o < 64; o++) acc_s[o] = bias[o];
#pragma unroll 8
    for (int i = 0; i < 64; i++) {
      float hi = hbuf[i * 128 + t];
      const float* Wr = W + i * 64;
#pragma unroll
      for (int o = 0; o < 64; o++) acc_s[o] = fmaf(Wr[o], hi, acc_s[o]);
    }
    float s = 0.0f, s2 = 0.0f;
#pragma unroll
    for (int o = 0; o < 64; o++) { s += acc_s[o]; s2 += acc_s[o] * acc_s[o]; }
    float mu = s * (1.0f / 64.0f);
    float var = s2 * (1.0f / 64.0f) - mu * mu;
    float inv = rsqrtf(var + LN_EPS);
    float aslope = prelu_a[li + 1];
    const float* gp = ln_g + (li + 1) * 64;
    const float* be = ln_b + (li + 1) * 64;
    if (li < 2) {
#pragma unroll
      for (int o = 0; o < 64; o++) {
        float v = gp[o] * ((acc_s[o] - mu) * inv) + be[o];
        v = v > 0.0f ? v : aslope * v;
        hbuf[o * 128 + t] = v;
      }
    } else {
#pragma unroll
      for (int o = 0; o < 64; o++) {
        float v = gp[o] * ((acc_s[o] - mu) * inv) + be[o];
        h[o] = v > 0.0f ? v : aslope * v;
      }
    }
  }

  float cnt = ntr[b];

  // ---- pack own h into 32 bf16x2 hi/lo words (word w = channels 2w,2w+1) --
  u32 hpk_hi[32], hpk_lo[32];
#pragma unroll
  for (int w = 0; w < 32; w++) {
    float f0 = h[2 * w], f1 = h[2 * w + 1];
    u32 h0 = rn_hi32(f0);
    u32 h1 = rn_hi32(f1);
    float l0 = f0 - __uint_as_float(h0);
    float l1 = f1 - __uint_as_float(h1);
    hpk_hi[w] = (h0 >> 16) | h1;
    hpk_lo[w] = rn_b16(l0) | (rn_b16(l1) << 16);
  }

  // ---- hidden layer 3 via MFMA, B built by register shuffles ----
  {
    const int li = 3;
    u32x4 wh[4][2], wl[4][2];
#pragma unroll
    for (int m = 0; m < 4; m++)
#pragma unroll
      for (int ks = 0; ks < 2; ks++) {
        int fi = ((li * 4 + m) * 2 + ks) * 64 + l;
        wh[m][ks] = whi[fi];
        wl[m][ks] = wlo[fi];
      }
    f32x4 g4[4], b4[4], bias4[4];
#pragma unroll
    for (int m = 0; m < 4; m++) {
      g4[m] = *(const f32x4*)(ln_g + (li + 1) * 64 + 16 * m + 4 * g);
      b4[m] = *(const f32x4*)(ln_b + (li + 1) * 64 + 16 * m + 4 * g);
      bias4[m] = *(const f32x4*)(bh + li * 64 + 16 * m + 4 * g);
    }
    float aslope = prelu_a[li + 1];

    f32x4 acc[4][4];  // [m][nt]
#pragma unroll
    for (int m = 0; m < 4; m++)
#pragma unroll
      for (int nt = 0; nt < 4; nt++) acc[m][nt] = bias4[m];

#pragma unroll
    for (int nt = 0; nt < 4; nt++) {
      int src = c + 16 * nt;  // lane owning edge (point nt, slot c)
      u32x4 bhiW[2], bloW[2];
#pragma unroll
      for (int ks = 0; ks < 2; ks++)
#pragma unroll
        for (int gw = 0; gw < 4; gw++)
#pragma unroll
          for (int j = 0; j < 4; j++) {
            u32 th = (u32)__shfl((int)hpk_hi[16 * ks + 4 * gw + j], src, 64);
            u32 tl = (u32)__shfl((int)hpk_lo[16 * ks + 4 * gw + j], src, 64);
            if (g == gw) {
              bhiW[ks][j] = th;
              bloW[ks][j] = tl;
            }
          }
#pragma unroll
      for (int ks = 0; ks < 2; ks++) {
        short8 bh_ = __builtin_bit_cast(short8, bhiW[ks]);
        short8 bl_ = __builtin_bit_cast(short8, bloW[ks]);
#pragma unroll
        for (int m = 0; m < 4; m++) {
          short8 ah = __builtin_bit_cast(short8, wh[m][ks]);
          short8 al = __builtin_bit_cast(short8, wl[m][ks]);
          acc[m][nt] = __builtin_amdgcn_mfma_f32_16x16x32_bf16(ah, bh_, acc[m][nt], 0, 0, 0);
          acc[m][nt] = __builtin_amdgcn_mfma_f32_16x16x32_bf16(ah, bl_, acc[m][nt], 0, 0, 0);
          acc[m][nt] = __builtin_amdgcn_mfma_f32_16x16x32_bf16(al, bh_, acc[m][nt], 0, 0, 0);
        }
      }
    }

    // LN + PReLU per edge-tile nt (row sums across g via xor 16/32)
#pragma unroll
    for (int nt = 0; nt < 4; nt++) {
      float s = 0.0f, s2 = 0.0f;
#pragma unroll
      for (int m = 0; m < 4; m++)
#pragma unroll
        for (int v = 0; v < 4; v++) {
          float x = acc[m][nt][v];
          s += x;
          s2 = fmaf(x, x, s2);
        }
      s += __shfl_xor(s, 16, 64);
      s2 += __shfl_xor(s2, 16, 64);
      s += __shfl_xor(s, 32, 64);
      s2 += __shfl_xor(s2, 32, 64);
      float mu = s * (1.0f / 64.0f);
      float var = s2 * (1.0f / 64.0f) - mu * mu;
      float inv = rsqrtf(var + LN_EPS);
#pragma unroll
      for (int m = 0; m < 4; m++)
#pragma unroll
        for (int v = 0; v < 4; v++) {
          float x = (acc[m][nt][v] - mu) * inv;
          x = g4[m][v] * x + b4[m][v];
          acc[m][nt][v] = x > 0.0f ? x : aslope * x;
        }
    }

    // masked mean over K, write out
    float n_safe = (cnt == 0.0f) ? 1.0f : cnt;
    float rinv = 1.0f / n_safe;
    float msk = ((float)c < cnt) ? 1.0f : 0.0f;
#pragma unroll
    for (int nt = 0; nt < 4; nt++)
#pragma unroll
      for (int m = 0; m < 4; m++) {
        f32x4 r;
#pragma unroll
        for (int v = 0; v < 4; v++) {
          float x = acc[m][nt][v] * msk;
          x += __shfl_xor(x, 1, 64);
          x += __shfl_xor(x, 2, 64);
          x += __shfl_xor(x, 4, 64);
          x += __shfl_xor(x, 8, 64);
          r[v] = x * rinv;
        }
        if (c == 0)
          *(f32x4*)(out + (size_t)(pbase + nt) * 64 + 16 * m + 4 * g) = r;
      }
  }
}

// ---------------------------------------------------------------------------
extern "C" void kernel_launch(void* const* d_in, const int* in_sizes, int n_in,
                              void* d_out, int out_size, void* d_ws, size_t ws_size,
                              hipStream_t stream) {
  const float* points  = (const float*)d_in[0];
  const float* x       = (const float*)d_in[1];
  const int*   mask    = (const int*)d_in[2];
  const float* W0      = (const float*)d_in[3];
  const float* b0      = (const float*)d_in[4];
  const float* Wh      = (const float*)d_in[5];
  const float* bh      = (const float*)d_in[6];
  const float* ln_g    = (const float*)d_in[7];
  const float* ln_b    = (const float*)d_in[8];
  const float* prelu_a = (const float*)d_in[9];
  float* out = (float*)d_out;

  char* ws = (char*)d_ws;
  int*   knn  = (int*)ws;                                    // 1 MB
  float* p_c  = (float*)(ws + (1 << 20));                    // 4 MB
  float* p_n  = (float*)(ws + (1 << 20) + (4 << 20));        // 4 MB
  u32x4* whi  = (u32x4*)(ws + (9 << 20));                    // 32 KB
  u32x4* wlo  = (u32x4*)(ws + (9 << 20) + (32 << 10));       // 32 KB
  float* WhT  = (float*)(ws + (9 << 20) + (64 << 10));       // 64 KB
  float* ntr  = (float*)(ws + (9 << 20) + (128 << 10));

  prep_kernel<<<28, 256, 0, stream>>>(Wh, whi, wlo, WhT, mask, ntr);
  knn_kernel<<<4096, 256, 0, stream>>>(points, mask, knn);
  precompute_kernel<<<256, 256, 0, stream>>>(x, W0, b0, p_c, p_n);
  mlp_hybrid2_kernel<<<2048, 128, 0, stream>>>(p_c, p_n, knn, WhT, whi, wlo, bh,
                                               ln_g, ln_b, prelu_a, ntr, out);
}